// Round 4
// baseline (360.611 us; speedup 1.0000x reference)
//
#include <hip/hip_runtime.h>
#include <hip/hip_fp16.h>
#include <hip/hip_bf16.h>
#include <math.h>

// ---------------------------------------------------------------------------
// EdgeAttnConv: out[d] = x[d] + (Σ_{e: dst=d} w_e·(z[src_e] + ea_e@We)) / (Σ w_e + 1e-8)
//   w_e = exp(score_e - max_d),  score_e = leaky_relu(zs[src]+zd[dst]+ea_e·weA, 0.2)
//   z = x@Wn (stored bf16), zs = z@att_src, zd = z@att_dst, weA = We@att_edge
// Identity: Σ w·(ea@We) = (Σ w·ea)@We  -> e=[E,64] never materialized.
// CSR build: countpos (atomics) -> offsets -> scatter writes FAT 64B records
//   {src, score, ea as 16×f16} (full-sector scattered writes, ea embedded so
//   k_agg never random-gathers ea). k_agg streams records + gathers bf16 z.
// ---------------------------------------------------------------------------

__device__ __forceinline__ float wave_max64(float v) {
#pragma unroll
  for (int o = 32; o > 0; o >>= 1) v = fmaxf(v, __shfl_xor(v, o));
  return v;
}
__device__ __forceinline__ float wave_sum64(float v) {
#pragma unroll
  for (int o = 32; o > 0; o >>= 1) v += __shfl_xor(v, o);
  return v;
}
__device__ __forceinline__ unsigned pack_h2(float a, float b) {
  __half2 h = __floats2half2_rn(a, b);
  return *reinterpret_cast<unsigned*>(&h);
}
__device__ __forceinline__ float bf2f(unsigned short u) {
  return __uint_as_float(((unsigned)u) << 16);
}
__device__ __forceinline__ float h2f(unsigned short u) {
  __half h = *reinterpret_cast<__half*>(&u);
  return __half2float(h);
}

// --- tiny prep: weA = We @ att_edge (16), zero global scan base -------------
__global__ __launch_bounds__(64) void k_prep(const float* __restrict__ We,
                                             const float* __restrict__ att_edge,
                                             float* __restrict__ weA,
                                             int* __restrict__ total) {
  int t = threadIdx.x;
  if (t < 16) {
    float a = 0.f;
#pragma unroll
    for (int c = 0; c < 64; ++c) a = fmaf(We[t * 64 + c], att_edge[c], a);
    weA[t] = a;
  }
  if (t == 16) *total = 0;
}

// --- count + per-edge position within its dst bucket (the ONLY atomic pass) -
__global__ __launch_bounds__(256) void k_countpos(const int* __restrict__ dst,
                                                  int* __restrict__ count,
                                                  int* __restrict__ pos, int e) {
  int i = blockIdx.x * 256 + threadIdx.x;
  if (i < e) pos[i] = atomicAdd(&count[dst[i]], 1);
}

// --- node kernel: wave per row. zb=bf16(x@Wn), zs=z·att_src, zd=z·att_dst ---
__global__ __launch_bounds__(256) void k_node(
    const float* __restrict__ x, const float* __restrict__ Wn,
    const float* __restrict__ att_src, const float* __restrict__ att_dst,
    unsigned short* __restrict__ zb, float* __restrict__ zs,
    float* __restrict__ zd, int n) {
  const int lane = threadIdx.x & 63;
  const int wid = (blockIdx.x * blockDim.x + threadIdx.x) >> 6;
  const int nw = (gridDim.x * blockDim.x) >> 6;
  float wn[64];  // my output column of Wn
#pragma unroll
  for (int k = 0; k < 64; ++k) wn[k] = Wn[k * 64 + lane];
  const float as = att_src[lane], ad = att_dst[lane];
  for (int r = wid; r < n; r += nw) {
    float xv = x[(size_t)r * 64 + lane];
    float a0 = 0.f, a1 = 0.f, a2 = 0.f, a3 = 0.f;
#pragma unroll
    for (int k = 0; k < 64; k += 4) {
      a0 = fmaf(__shfl(xv, k), wn[k], a0);
      a1 = fmaf(__shfl(xv, k + 1), wn[k + 1], a1);
      a2 = fmaf(__shfl(xv, k + 2), wn[k + 2], a2);
      a3 = fmaf(__shfl(xv, k + 3), wn[k + 3], a3);
    }
    float acc = (a0 + a1) + (a2 + a3);
    __hip_bfloat16 b = __float2bfloat16(acc);
    zb[(size_t)r * 64 + lane] = *reinterpret_cast<unsigned short*>(&b);
    float ps = wave_sum64(acc * as);
    float pd = wave_sum64(acc * ad);
    if (lane == 0) {
      zs[r] = ps;
      zd[r] = pd;
    }
  }
}

// --- offsets: block scan of counts + one atomic per block (order-free) ------
__global__ __launch_bounds__(256) void k_offsets(const int* __restrict__ count,
                                                 int* __restrict__ start,
                                                 int* __restrict__ total, int n) {
  __shared__ int sdata[256];
  __shared__ int sbase;
  const int tid = threadIdx.x;
  const int i = blockIdx.x * 256 + tid;
  int c = (i < n) ? count[i] : 0;
  int v = c;
  sdata[tid] = v;
  __syncthreads();
  for (int off = 1; off < 256; off <<= 1) {
    int t = (tid >= off) ? sdata[tid - off] : 0;
    __syncthreads();
    v += t;
    sdata[tid] = v;
    __syncthreads();
  }
  if (tid == 255) sbase = atomicAdd(total, v);
  __syncthreads();
  if (i < n) start[i] = sbase + (v - c);
}

// --- scatter: atomic-free heavy pass. 64B record {src, score, ea f16} -------
__global__ __launch_bounds__(256) void k_scatter(
    const int* __restrict__ src, const int* __restrict__ dst,
    const int* __restrict__ pos, const float* __restrict__ zs,
    const float* __restrict__ zd, const float* __restrict__ ea,
    const float* __restrict__ weA, const int* __restrict__ start,
    uint4* __restrict__ es, int e) {
  int i = blockIdx.x * 256 + threadIdx.x;
  if (i >= e) return;
  int s = src[i], d = dst[i], p = pos[i];
  size_t slot = (size_t)start[d] + p;  // start[] gather: L2-resident (400 KB)
  const float4* eap = (const float4*)(ea + (size_t)i * 16);
  float4 q0 = eap[0], q1 = eap[1], q2 = eap[2], q3 = eap[3];
  float sed = q0.x * weA[0] + q0.y * weA[1] + q0.z * weA[2] + q0.w * weA[3] +
              q1.x * weA[4] + q1.y * weA[5] + q1.z * weA[6] + q1.w * weA[7] +
              q2.x * weA[8] + q2.y * weA[9] + q2.z * weA[10] + q2.w * weA[11] +
              q3.x * weA[12] + q3.y * weA[13] + q3.z * weA[14] + q3.w * weA[15];
  float sv = zs[s] + zd[d] + sed;
  float sc = (sv > 0.f) ? sv : 0.2f * sv;
  uint4* rp = es + slot * 4;  // record = 4 × uint4 = 64B, full-sector write
  rp[0] = make_uint4((unsigned)s, __float_as_uint(sc), 0u, 0u);
  rp[1] = make_uint4(pack_h2(q0.x, q0.y), pack_h2(q0.z, q0.w),
                     pack_h2(q1.x, q1.y), pack_h2(q1.z, q1.w));
  rp[2] = make_uint4(pack_h2(q2.x, q2.y), pack_h2(q2.z, q2.w),
                     pack_h2(q3.x, q3.y), pack_h2(q3.z, q3.w));
  rp[3] = make_uint4(0u, 0u, 0u, 0u);
}

// --- aggregate: wave per node, grid-stride, next-node prefetch --------------
__global__ __launch_bounds__(256) void k_agg(
    const float* __restrict__ x, const unsigned short* __restrict__ zb,
    const float* __restrict__ We, const int* __restrict__ start,
    const int* __restrict__ count, const uint4* __restrict__ es,
    float* __restrict__ out, int n) {
  const int lane = threadIdx.x & 63;
  const int grp = lane >> 4;   // 4 groups of 16; group handles edges jj%4==grp
  const int gl = lane & 15;    // owns columns 4*gl..4*gl+3
  const int nw = (gridDim.x * blockDim.x) >> 6;
  int d = (blockIdx.x * blockDim.x + threadIdx.x) >> 6;
  if (d >= n) return;

  const uint2 HD0 = make_uint2(0u, __float_as_uint(-1e30f));
  const unsigned short* esu = (const unsigned short*)es;  // 32 u16 per record

  int s0 = start[d], cnt = count[d];
  uint2 hd = HD0;
  if (lane < cnt) hd = *(const uint2*)(es + ((size_t)s0 + lane) * 4);

  while (d < n) {
    // prefetch next node's header chunk while computing this one
    int dn = d + nw;
    int sn0 = 0, cn = 0;
    uint2 hdn = HD0;
    if (dn < n) {
      sn0 = start[dn];
      cn = count[dn];
      if (lane < cn) hdn = *(const uint2*)(es + ((size_t)sn0 + lane) * 4);
    }

    float m = -1e30f, dsum = 0.f, ag = 0.f;
    float4 msg = make_float4(0.f, 0.f, 0.f, 0.f);

    for (int c0 = 0; c0 < cnt; c0 += 64) {
      const int nc = min(64, cnt - c0);
      const bool act = lane < nc;
      uint2 cur = hd;
      if (c0 > 0)  // rare (deg > 64)
        cur = act ? *(const uint2*)(es + ((size_t)s0 + c0 + lane) * 4) : HD0;
      float sc = act ? __uint_as_float(cur.y) : -1e30f;
      // online-softmax chunk combine
      float mc = wave_max64(sc);
      float mnew = fmaxf(m, mc);
      float rs = __expf(m - mnew);
      float w = act ? __expf(sc - mnew) : 0.f;
      m = mnew;
      dsum = dsum * rs + w;
      msg.x *= rs; msg.y *= rs; msg.z *= rs; msg.w *= rs;
      ag *= rs;
      int sv = (int)cur.x;
      // gather: group grp handles edges jj = 4t+grp; unroll x2 for ILP
      const int steps = (nc + 3) >> 2;
      int t = 0;
      for (; t + 2 <= steps; t += 2) {
        int jj0 = (t << 2) + grp, jj1 = jj0 + 4;
        float w0 = __shfl(w, jj0), w1 = __shfl(w, jj1);
        int s0v = __shfl(sv, jj0), s1v = __shfl(sv, jj1);
        ushort4 z0 = *(const ushort4*)(zb + (size_t)s0v * 64 + gl * 4);
        ushort4 z1 = *(const ushort4*)(zb + (size_t)s1v * 64 + gl * 4);
        unsigned short a0u = esu[((size_t)s0 + c0 + jj0) * 32 + 8 + gl];
        unsigned short a1u = esu[((size_t)s0 + c0 + jj1) * 32 + 8 + gl];
        msg.x = fmaf(w0, bf2f(z0.x), fmaf(w1, bf2f(z1.x), msg.x));
        msg.y = fmaf(w0, bf2f(z0.y), fmaf(w1, bf2f(z1.y), msg.y));
        msg.z = fmaf(w0, bf2f(z0.z), fmaf(w1, bf2f(z1.z), msg.z));
        msg.w = fmaf(w0, bf2f(z0.w), fmaf(w1, bf2f(z1.w), msg.w));
        ag = fmaf(w0, h2f(a0u), fmaf(w1, h2f(a1u), ag));
      }
      if (t < steps) {
        int jj0 = (t << 2) + grp;
        float w0 = __shfl(w, jj0);
        int s0v = __shfl(sv, jj0);
        ushort4 z0 = *(const ushort4*)(zb + (size_t)s0v * 64 + gl * 4);
        unsigned short a0u = esu[((size_t)s0 + c0 + jj0) * 32 + 8 + gl];
        msg.x = fmaf(w0, bf2f(z0.x), msg.x);
        msg.y = fmaf(w0, bf2f(z0.y), msg.y);
        msg.z = fmaf(w0, bf2f(z0.z), msg.z);
        msg.w = fmaf(w0, bf2f(z0.w), msg.w);
        ag = fmaf(w0, h2f(a0u), ag);
      }
    }

    float dtot = wave_sum64(dsum);
    // combine the 4 groups' partials
    msg.x += __shfl_xor(msg.x, 16); msg.x += __shfl_xor(msg.x, 32);
    msg.y += __shfl_xor(msg.y, 16); msg.y += __shfl_xor(msg.y, 32);
    msg.z += __shfl_xor(msg.z, 16); msg.z += __shfl_xor(msg.z, 32);
    msg.w += __shfl_xor(msg.w, 16); msg.w += __shfl_xor(msg.w, 32);
    ag += __shfl_xor(ag, 16); ag += __shfl_xor(ag, 32);

    // evec = (Σ w·ea) @ We, per-lane float4 of columns 4gl..4gl+3
    const float4* We4 = (const float4*)We;
    float4 evec = make_float4(0.f, 0.f, 0.f, 0.f);
#pragma unroll
    for (int k = 0; k < 16; ++k) {
      float agk = __shfl(ag, k);
      float4 wef = We4[k * 16 + gl];
      evec.x = fmaf(agk, wef.x, evec.x);
      evec.y = fmaf(agk, wef.y, evec.y);
      evec.z = fmaf(agk, wef.z, evec.z);
      evec.w = fmaf(agk, wef.w, evec.w);
    }

    if (grp == 0) {
      float inv = 1.f / (dtot + 1e-8f);
      const float4 xr = *(const float4*)(x + (size_t)d * 64 + gl * 4);
      float4 r;
      r.x = fmaf(msg.x + evec.x, inv, xr.x);
      r.y = fmaf(msg.y + evec.y, inv, xr.y);
      r.z = fmaf(msg.z + evec.z, inv, xr.z);
      r.w = fmaf(msg.w + evec.w, inv, xr.w);
      *(float4*)(out + (size_t)d * 64 + gl * 4) = r;
    }

    d = dn; s0 = sn0; cnt = cn; hd = hdn;
  }
}

extern "C" void kernel_launch(void* const* d_in, const int* in_sizes, int n_in,
                              void* d_out, int out_size, void* d_ws, size_t ws_size,
                              hipStream_t stream) {
  const float* x = (const float*)d_in[0];
  const int* ei = (const int*)d_in[1];
  const float* ea = (const float*)d_in[2];
  const float* Wn = (const float*)d_in[3];
  const float* We = (const float*)d_in[4];
  const float* att_src = (const float*)d_in[5];
  const float* att_dst = (const float*)d_in[6];
  const float* att_edge = (const float*)d_in[7];
  float* out = (float*)d_out;

  const int N = in_sizes[0] / 64;
  const int E = in_sizes[1] / 2;
  const int* src = ei;
  const int* dst = ei + E;

  // workspace carve (256B aligned)
  char* p = (char*)d_ws;
  auto carve = [&](size_t bytes) {
    void* q = (void*)p;
    p += (bytes + 255) & ~(size_t)255;
    return q;
  };
  unsigned short* zb = (unsigned short*)carve((size_t)N * 64 * 2);
  float* zs = (float*)carve((size_t)N * sizeof(float));
  float* zd = (float*)carve((size_t)N * sizeof(float));
  int* count = (int*)carve((size_t)N * sizeof(int));
  int* startp = (int*)carve((size_t)N * sizeof(int));
  int* pos = (int*)carve((size_t)E * sizeof(int));
  float* weA = (float*)carve(64);
  int* total = (int*)carve(64);
  uint4* es = (uint4*)carve((size_t)E * 64);  // 64B records

  hipMemsetAsync(count, 0, (size_t)N * sizeof(int), stream);
  k_prep<<<1, 64, 0, stream>>>(We, att_edge, weA, total);
  k_countpos<<<(E + 255) / 256, 256, 0, stream>>>(dst, count, pos, E);
  k_node<<<2048, 256, 0, stream>>>(x, Wn, att_src, att_dst, zb, zs, zd, N);
  k_offsets<<<(N + 255) / 256, 256, 0, stream>>>(count, startp, total, N);
  k_scatter<<<(E + 255) / 256, 256, 0, stream>>>(src, dst, pos, zs, zd, ea, weA,
                                                 startp, es, E);
  k_agg<<<4096, 256, 0, stream>>>(x, zb, We, startp, count, es, out, N);
}